// Round 17
// baseline (162.361 us; speedup 1.0000x reference)
//
#include <hip/hip_runtime.h>
#include <hip/hip_bf16.h>

#define N_ATOMS 20000
#define N_BONDS 200000
#define MAX_DEG 12
#define IN_DIM 256
#define BOND_DIM 128
#define OUT_DIM 512
#define N_HEADS 8
#define HEAD_DIM 64

typedef __attribute__((ext_vector_type(8))) short short8v;
typedef __attribute__((ext_vector_type(4))) float f32x4;

static __device__ __forceinline__ float bf2f(unsigned int u) {
    union { unsigned int i; float f; } c;
    c.i = (u & 0xffffu) << 16;
    return c.f;
}
static __device__ __forceinline__ unsigned short f2bf(float f) {
    union { float f; unsigned int i; } c;
    c.f = f;
    unsigned int x = c.i;
    x += 0x7fffu + ((x >> 16) & 1u);   // round-to-nearest-even
    return (unsigned short)(x >> 16);
}

// ---------------------------------------------------------------------------
// PREP (fused): WtA (blocks 0..511), WtB (512..767), u_edgeB16/c_edge (768..771)
// u_edgeB16[16][128] bf16: rows 0..7 = W_bond_head . att_edge, rows 8..15 = 0.
// ---------------------------------------------------------------------------
__global__ __launch_bounds__(256) void prep_kernel(
    const float* __restrict__ W_atom, const float* __restrict__ W_bond,
    const float* __restrict__ att_edge, const float* __restrict__ b_bond,
    unsigned short* __restrict__ WtA, unsigned short* __restrict__ WtB,
    unsigned short* __restrict__ u_edgeB16, float* __restrict__ c_edge) {
    const int b = blockIdx.x;
    if (b < 512) {                      // WtA[n][k] = bf16(W_atom[k][n]), K=256
        int id = b * 256 + threadIdx.x;
        int n = id >> 8, k = id & 255;
        WtA[id] = f2bf(W_atom[(size_t)k * 512 + n]);
    } else if (b < 768) {               // WtB[n][k] = bf16(W_bond[k][n]), K=128
        int id = (b - 512) * 256 + threadIdx.x;
        int n = id >> 7, k = id & 127;
        WtB[id] = f2bf(W_bond[(size_t)k * 512 + n]);
    } else {                            // u_edgeB16 / c_edge
        int tid = (b - 768) * 256 + threadIdx.x;
        if (tid >= 1024) return;
        int h = tid >> 7, c = tid & 127;
        const float* wrow = W_bond + (size_t)c * 512 + h * 64;
        const float* ae = att_edge + h * 64;
        float s = 0.f;
        #pragma unroll 8
        for (int k = 0; k < 64; ++k) s += wrow[k] * ae[k];
        u_edgeB16[h * 128 + c] = f2bf(s);
        u_edgeB16[(h + 8) * 128 + c] = 0;          // zero pad rows 8..15
        if (c == 0) {
            float cs = 0.f;
            const float* bb = b_bond + h * 64;
            for (int k = 0; k < 64; ++k) cs += bb[k] * ae[k];
            c_edge[h] = cs;
        }
    }
}

// ---------------------------------------------------------------------------
// ESCORE (standalone, ZERO LDS): 64 bonds/block, 3125 blocks.
// All 8 edge loads hoisted (8 in flight); registers feed both the bf16 edgeB
// write and the MFMA A-fragment for score = edge . u_edge^T.
// ---------------------------------------------------------------------------
__global__ __launch_bounds__(256) void escore_kernel(
    const float* __restrict__ edge, const unsigned short* __restrict__ u_edgeB16,
    const float* __restrict__ c_edge, float* __restrict__ score_edge,
    unsigned short* __restrict__ edgeB) {
    const int t = threadIdx.x;
    const int w = t >> 6, l = t & 63;
    const int m16 = l & 15, g4 = l >> 4;
    const size_t b0 = (size_t)blockIdx.x * 64;
    const int arow = (w << 4) + m16;               // bond row within block
    const float* Ar = edge + (b0 + arow) * 128 + (g4 << 3);

    // B fragments: u_edgeB16[16][128], B-row = m16 (head; rows>=8 zero)
    short8v bfr[4];
    #pragma unroll
    for (int ks = 0; ks < 4; ++ks)
        bfr[ks] = *(const short8v*)(u_edgeB16 + (size_t)m16 * 128 + (ks << 5) + (g4 << 3));

    // hoist ALL edge loads: 8 x 16B in flight
    f32x4 a0[4], a1[4];
    #pragma unroll
    for (int ks = 0; ks < 4; ++ks) {
        a0[ks] = *(const f32x4*)(Ar + (ks << 5));
        a1[ks] = *(const f32x4*)(Ar + (ks << 5) + 4);
    }

    f32x4 acc = {};
    unsigned short* ebase = edgeB + (b0 + arow) * 128 + (g4 << 3);
    #pragma unroll
    for (int ks = 0; ks < 4; ++ks) {
        union { unsigned short us[8]; short8v v; uint4 q; } pk;
        pk.us[0] = f2bf(a0[ks][0]); pk.us[1] = f2bf(a0[ks][1]);
        pk.us[2] = f2bf(a0[ks][2]); pk.us[3] = f2bf(a0[ks][3]);
        pk.us[4] = f2bf(a1[ks][0]); pk.us[5] = f2bf(a1[ks][1]);
        pk.us[6] = f2bf(a1[ks][2]); pk.us[7] = f2bf(a1[ks][3]);
        *(uint4*)(ebase + (ks << 5)) = pk.q;       // bf16 edge copy
        acc = __builtin_amdgcn_mfma_f32_16x16x32_bf16(pk.v, bfr[ks], acc, 0, 0, 0);
    }
    // epilogue: C row = g4*4+r (bond within wave), col = m16 (head, <8 valid)
    if (m16 < 8) {
        const float ce = c_edge[m16];
        const size_t sbase = b0 + (w << 4) + (g4 << 2);
        #pragma unroll
        for (int r = 0; r < 4; ++r)
            score_edge[(sbase + r) * 8 + m16] = acc[r] + ce;
    }
}

// ---------------------------------------------------------------------------
// ATOM GEMM (round-4 proven): tiles 64x64x64, 4 waves, XCD-chunked swizzle.
// ---------------------------------------------------------------------------
__global__ __launch_bounds__(256) void gemm_kernel(
    const float* __restrict__ A, const unsigned short* __restrict__ Wt,
    const float* __restrict__ bias, unsigned short* __restrict__ H,
    int M, int K, int nbm) {
    __shared__ unsigned short Als[64 * 64];
    __shared__ unsigned short Bls[64 * 64];
    const int t = threadIdx.x;
    const int wgid = (blockIdx.x & 7) * nbm + (blockIdx.x >> 3);
    const int bn = wgid & 7;
    const int bm = wgid >> 3;
    const int w = t >> 6;
    const int l = t & 63;

    f32x4 acc[4] = {};

    const int nk = K >> 6;
    for (int kk = 0; kk < nk; ++kk) {
        #pragma unroll
        for (int i = 0; i < 2; ++i) {
            int c = t + i * 256;
            int row = c >> 3;
            int k8 = (c & 7) << 3;
            int grow = (bm << 6) + row;
            float f[8];
            if (grow < M) {
                const float* src = A + (size_t)grow * K + (kk << 6) + k8;
                float4 v0 = *(const float4*)src;
                float4 v1 = *(const float4*)(src + 4);
                f[0] = v0.x; f[1] = v0.y; f[2] = v0.z; f[3] = v0.w;
                f[4] = v1.x; f[5] = v1.y; f[6] = v1.z; f[7] = v1.w;
            } else {
                #pragma unroll
                for (int j = 0; j < 8; ++j) f[j] = 0.f;
            }
            union { unsigned short us[8]; uint4 v; } pk;
            #pragma unroll
            for (int j = 0; j < 8; ++j) pk.us[j] = f2bf(f[j]);
            int byte = ((row << 7) + (k8 << 1)) ^ ((row & 7) << 4);
            *(uint4*)((char*)Als + byte) = pk.v;
        }
        #pragma unroll
        for (int i = 0; i < 2; ++i) {
            int c = t + i * 256;
            int row = c >> 3;
            int k8 = (c & 7) << 3;
            int gn = (bn << 6) + row;
            uint4 v = *(const uint4*)(Wt + (size_t)gn * K + (kk << 6) + k8);
            int byte = ((row << 7) + (k8 << 1)) ^ ((row & 7) << 4);
            *(uint4*)((char*)Bls + byte) = v;
        }
        __syncthreads();

        const int m = l & 15;
        const int kg = (l >> 4) << 3;
        #pragma unroll
        for (int ks = 0; ks < 2; ++ks) {
            int kcol = (ks << 5) + kg;
            int arow = (w << 4) + m;
            short8v a = *(short8v*)((char*)Als +
                (((arow << 7) + (kcol << 1)) ^ ((arow & 7) << 4)));
            #pragma unroll
            for (int nt = 0; nt < 4; ++nt) {
                int nrow = (nt << 4) + m;
                short8v b = *(short8v*)((char*)Bls +
                    (((nrow << 7) + (kcol << 1)) ^ ((nrow & 7) << 4)));
                acc[nt] = __builtin_amdgcn_mfma_f32_16x16x32_bf16(a, b, acc[nt], 0, 0, 0);
            }
        }
        __syncthreads();
    }

    const int m = l & 15;
    const int rbase = (bm << 6) + (w << 4) + ((l >> 4) << 2);
    #pragma unroll
    for (int nt = 0; nt < 4; ++nt) {
        int col = (bn << 6) + (nt << 4) + m;
        float bv = bias[col];
        #pragma unroll
        for (int r = 0; r < 4; ++r) {
            int grow = rbase + r;
            if (grow < M) H[(size_t)grow * 512 + col] = f2bf(acc[nt][r] + bv);
        }
    }
}

// ---------------------------------------------------------------------------
// Per-atom score tables from hA: s_src_all[n][h], s_dst_all[n][h].
// ---------------------------------------------------------------------------
__global__ __launch_bounds__(256) void sdots_kernel(
    const unsigned short* __restrict__ hA,
    const float* __restrict__ att_src, const float* __restrict__ att_dst,
    float* __restrict__ s_src_all, float* __restrict__ s_dst_all) {
    const int w = threadIdx.x >> 6, l = threadIdx.x & 63;
    const int n = blockIdx.x * 4 + w;
    if (n >= N_ATOMS) return;
    float4 s0 = *(const float4*)(att_src + l * 8);
    float4 s1 = *(const float4*)(att_src + l * 8 + 4);
    float4 d0 = *(const float4*)(att_dst + l * 8);
    float4 d1 = *(const float4*)(att_dst + l * 8 + 4);
    uint4 u = *(const uint4*)(hA + (size_t)n * 512 + l * 8);
    float fa[8];
    fa[0]=bf2f(u.x); fa[1]=bf2f(u.x>>16); fa[2]=bf2f(u.y); fa[3]=bf2f(u.y>>16);
    fa[4]=bf2f(u.z); fa[5]=bf2f(u.z>>16); fa[6]=bf2f(u.w); fa[7]=bf2f(u.w>>16);
    float ps = fa[0]*s0.x + fa[1]*s0.y + fa[2]*s0.z + fa[3]*s0.w
             + fa[4]*s1.x + fa[5]*s1.y + fa[6]*s1.z + fa[7]*s1.w;
    float pd = fa[0]*d0.x + fa[1]*d0.y + fa[2]*d0.z + fa[3]*d0.w
             + fa[4]*d1.x + fa[5]*d1.y + fa[6]*d1.z + fa[7]*d1.w;
    ps += __shfl_xor(ps, 1); ps += __shfl_xor(ps, 2); ps += __shfl_xor(ps, 4);
    pd += __shfl_xor(pd, 1); pd += __shfl_xor(pd, 2); pd += __shfl_xor(pd, 4);
    if ((l & 7) == 0) {
        s_src_all[n * 8 + (l >> 3)] = ps;
        s_dst_all[n * 8 + (l >> 3)] = pd;
    }
}

// ---------------------------------------------------------------------------
// Fused attention v7 (r14 proven): two-phase softmax, bf16 edge gather,
// bf16 hOut atom part. Lane l: head h=l>>3, channels l*8..+8, z (l&7)*16..+16.
// ---------------------------------------------------------------------------
__global__ __launch_bounds__(256) void attn_kernel(
    const unsigned short* __restrict__ hA,
    const unsigned short* __restrict__ edgeB,
    const float* __restrict__ s_src_all,
    const float* __restrict__ s_dst_all,
    const float* __restrict__ score_edge,
    const int* __restrict__ a2a,
    const int* __restrict__ a2b,
    unsigned short* __restrict__ hOut,
    unsigned short* __restrict__ Z) {
    const int w = threadIdx.x >> 6;
    const int l = threadIdx.x & 63;
    const int n = blockIdx.x * 4 + w;
    if (n >= N_ATOMS) return;
    const int h = l >> 3, sub = l & 7;

    const float ss = s_src_all[n * 8 + h];
    const int* pa = a2a + n * MAX_DEG;
    const int* pb = a2b + n * MAX_DEG;

    // ---- phase 1: all score gathers independent; exact softmax in regs ----
    float pw[12];
    #pragma unroll
    for (int d = 0; d < 12; ++d) {
        const int iad = pa[d];
        const int ibd = pb[d];
        float sd = s_dst_all[iad * 8 + h];
        float se = score_edge[ibd * 8 + h];
        float s = ss + sd + se;
        s = s > 0.f ? s : 0.2f * s;                 // leaky_relu(0.2)
        pw[d] = (iad != 0) ? s : -3e38f;            // sentinel for masked
    }
    float mx = fmaxf(
        fmaxf(fmaxf(fmaxf(pw[0], pw[1]), fmaxf(pw[2], pw[3])),
              fmaxf(fmaxf(pw[4], pw[5]), fmaxf(pw[6], pw[7]))),
        fmaxf(fmaxf(pw[8], pw[9]), fmaxf(pw[10], pw[11])));
    float lsum = 0.f;
    #pragma unroll
    for (int d = 0; d < 12; ++d) {
        pw[d] = __expf(pw[d] - mx);                 // masked: exp(-huge) = 0
        lsum += pw[d];
    }
    const float inv = lsum > 0.f ? 1.f / lsum : 0.f;

    // ---- phase 2: independent weighted accumulation (no chain) ----
    float acc[8], z[16];
    #pragma unroll
    for (int j = 0; j < 8; ++j) acc[j] = 0.f;
    #pragma unroll
    for (int j = 0; j < 16; ++j) z[j] = 0.f;

    #pragma unroll 2
    for (int d = 0; d < 12; ++d) {
        const int iad = pa[d];
        const int ibd = pb[d];
        const float p = pw[d];
        uint4 ua = *(const uint4*)(hA + (size_t)iad * 512 + l * 8);
        const unsigned short* ep = edgeB + (size_t)ibd * 128 + sub * 16;
        uint4 eb0 = *(const uint4*)(ep);
        uint4 eb1 = *(const uint4*)(ep + 8);

        float fa[8];
        fa[0]=bf2f(ua.x); fa[1]=bf2f(ua.x>>16); fa[2]=bf2f(ua.y); fa[3]=bf2f(ua.y>>16);
        fa[4]=bf2f(ua.z); fa[5]=bf2f(ua.z>>16); fa[6]=bf2f(ua.w); fa[7]=bf2f(ua.w>>16);

        #pragma unroll
        for (int j = 0; j < 8; ++j) acc[j] += p * fa[j];
        z[0]  += p * bf2f(eb0.x);       z[1]  += p * bf2f(eb0.x >> 16);
        z[2]  += p * bf2f(eb0.y);       z[3]  += p * bf2f(eb0.y >> 16);
        z[4]  += p * bf2f(eb0.z);       z[5]  += p * bf2f(eb0.z >> 16);
        z[6]  += p * bf2f(eb0.w);       z[7]  += p * bf2f(eb0.w >> 16);
        z[8]  += p * bf2f(eb1.x);       z[9]  += p * bf2f(eb1.x >> 16);
        z[10] += p * bf2f(eb1.y);       z[11] += p * bf2f(eb1.y >> 16);
        z[12] += p * bf2f(eb1.z);       z[13] += p * bf2f(eb1.z >> 16);
        z[14] += p * bf2f(eb1.w);       z[15] += p * bf2f(eb1.w >> 16);
    }

    // ---- atom part -> hOut (bf16) ----
    {
        union { unsigned int u[4]; uint4 v; } ap;
        #pragma unroll
        for (int i = 0; i < 4; ++i)
            ap.u[i] = (unsigned int)f2bf(acc[2*i] * inv)
                    | ((unsigned int)f2bf(acc[2*i+1] * inv) << 16);
        *(uint4*)(hOut + (size_t)n * 512 + l * 8) = ap.v;
    }

    // Z[n][h*128 + sub*16 .. +16] bf16: lane l -> 32B at l*32, coalesced
    union { unsigned int u[8]; uint4 v[2]; } zp;
    #pragma unroll
    for (int i = 0; i < 8; ++i)
        zp.u[i] = (unsigned int)f2bf(z[2*i] * inv)
                | ((unsigned int)f2bf(z[2*i+1] * inv) << 16);
    unsigned short* zdst = Z + (size_t)n * 1024 + l * 16;
    *(uint4*)zdst = zp.v[0];
    *(uint4*)(zdst + 8) = zp.v[1];
}

// ---------------------------------------------------------------------------
// Projection pass: out[n][h*64+j] = hOut + (Z[n][h] @ WtB_head) + b_bond.
// ---------------------------------------------------------------------------
__global__ __launch_bounds__(256, 4) void proj_kernel(
    const unsigned short* __restrict__ Z, const unsigned short* __restrict__ WtB,
    const float* __restrict__ b_bond, const unsigned short* __restrict__ hOut,
    float* __restrict__ out) {
    __shared__ unsigned short Bls[64 * 128];      // 16 KB
    const int t = threadIdx.x;
    const int w = t >> 6, l = t & 63;
    const int h = blockIdx.x & 7;                 // head
    const int mt = blockIdx.x >> 3;               // 0..312

    const int m16 = l & 15, g = l >> 4;
    const int arow = mt * 64 + (w << 4) + m16;

    const unsigned short* Zr = Z + (size_t)arow * 1024 + h * 128 + (g << 3);
    uint4 af[4];
    #pragma unroll
    for (int ks = 0; ks < 4; ++ks)
        af[ks] = *(const uint4*)(Zr + (ks << 5));

    {
        #pragma unroll
        for (int i = 0; i < 4; ++i) {
            int s = (w << 8) + (i << 6) + l;      // 0..1023
            int nrow = s >> 4;
            int kc = (s & 15) ^ (nrow & 7);
            const char* src = (const char*)WtB + (size_t)(h * 64 + nrow) * 256 + kc * 16;
            __builtin_amdgcn_global_load_lds(
                (const __attribute__((address_space(1))) void*)src,
                (__attribute__((address_space(3))) void*)((char*)Bls + (((w << 8) + (i << 6)) << 4)),
                16, 0, 0);
        }
    }
    __syncthreads();

    f32x4 acc[4] = {};
    #pragma unroll
    for (int ks = 0; ks < 4; ++ks) {
        short8v a = *(const short8v*)&af[ks];
        #pragma unroll
        for (int nt = 0; nt < 4; ++nt) {
            int nrow = (nt << 4) + m16;
            const short8v b = *(const short8v*)((const char*)Bls +
                ((nrow * 256 + (ks << 6) + (g << 4)) ^ ((nrow & 7) << 4)));
            acc[nt] = __builtin_amdgcn_mfma_f32_16x16x32_bf16(a, b, acc[nt], 0, 0, 0);
        }
    }

    const int rbase = mt * 64 + (w << 4) + (g << 2);
    #pragma unroll
    for (int nt = 0; nt < 4; ++nt) {
        int col = h * 64 + (nt << 4) + m16;
        float bv = b_bond[col];
        #pragma unroll
        for (int r = 0; r < 4; ++r) {
            int grow = rbase + r;
            if (grow < N_ATOMS) {
                float a0 = bf2f(hOut[(size_t)grow * 512 + col]);
                out[(size_t)grow * 512 + col] = a0 + acc[nt][r] + bv;
            }
        }
    }
}

// ---------------------------------------------------------------------------
extern "C" void kernel_launch(void* const* d_in, const int* in_sizes, int n_in,
                              void* d_out, int out_size, void* d_ws, size_t ws_size,
                              hipStream_t stream) {
    const float* x        = (const float*)d_in[0];
    const float* edge     = (const float*)d_in[1];
    const float* W_atom   = (const float*)d_in[2];
    const float* b_atom   = (const float*)d_in[3];
    const float* W_bond   = (const float*)d_in[4];
    const float* b_bond   = (const float*)d_in[5];
    const float* att_src  = (const float*)d_in[6];
    const float* att_dst  = (const float*)d_in[7];
    const float* att_edge = (const float*)d_in[8];
    const int*   a2a      = (const int*)d_in[9];
    const int*   a2b      = (const int*)d_in[10];
    float* out = (float*)d_out;

    char* ws = (char*)d_ws;
    unsigned short* hA      = (unsigned short*)ws;                    // 20,480,000
    unsigned short* Zb      = (unsigned short*)(ws + 20480000);       // 40,960,000
    unsigned short* WtA     = (unsigned short*)(ws + 61440000);       // 262,144
    unsigned short* WtB     = (unsigned short*)(ws + 61702144);       // 131,072
    float* s_src_all        = (float*)(ws + 61833216);                // 640,000
    float* s_dst_all        = (float*)(ws + 62473216);                // 640,000
    float* score_edge       = (float*)(ws + 63113216);                // 6,400,000
    unsigned short* u_edgeB16 = (unsigned short*)(ws + 69513216);     // 4,096
    float* c_edge           = (float*)(ws + 69517312);                // 64 (pad)
    unsigned short* hOut    = (unsigned short*)(ws + 69517376);       // 20,480,000
    unsigned short* edgeB   = (unsigned short*)(ws + 89997376);       // 51,200,000

    prep_kernel<<<772, 256, 0, stream>>>(W_atom, W_bond, att_edge, b_bond,
                                         WtA, WtB, u_edgeB16, c_edge);

    // standalone streaming escore (zero LDS) first, then the GEMM
    escore_kernel<<<3125, 256, 0, stream>>>(edge, u_edgeB16, c_edge,
                                            score_edge, edgeB);
    gemm_kernel<<<313 * 8, 256, 0, stream>>>(x, WtA, b_atom, hA,
                                             N_ATOMS, 256, 313);

    sdots_kernel<<<5000, 256, 0, stream>>>(hA, att_src, att_dst, s_src_all, s_dst_all);

    attn_kernel<<<5000, 256, 0, stream>>>(
        hA, edgeB, s_src_all, s_dst_all, score_edge, a2a, a2b, hOut, Zb);

    proj_kernel<<<313 * 8, 256, 0, stream>>>(Zb, WtB, b_bond, hOut, out);
}

// Round 18
// 148.772 us; speedup vs baseline: 1.0913x; 1.0913x over previous
//
#include <hip/hip_runtime.h>
#include <hip/hip_bf16.h>

#define N_ATOMS 20000
#define N_BONDS 200000
#define MAX_DEG 12
#define IN_DIM 256
#define BOND_DIM 128
#define OUT_DIM 512
#define N_HEADS 8
#define HEAD_DIM 64

typedef __attribute__((ext_vector_type(8))) short short8v;
typedef __attribute__((ext_vector_type(4))) float f32x4;

static __device__ __forceinline__ float bf2f(unsigned int u) {
    union { unsigned int i; float f; } c;
    c.i = (u & 0xffffu) << 16;
    return c.f;
}
static __device__ __forceinline__ unsigned short f2bf(float f) {
    union { float f; unsigned int i; } c;
    c.f = f;
    unsigned int x = c.i;
    x += 0x7fffu + ((x >> 16) & 1u);   // round-to-nearest-even
    return (unsigned short)(x >> 16);
}

// ---------------------------------------------------------------------------
// PREP (fused): WtA (blocks 0..511), WtB (512..767), u_edge/c_edge (768..771)
// ---------------------------------------------------------------------------
__global__ __launch_bounds__(256) void prep_kernel(
    const float* __restrict__ W_atom, const float* __restrict__ W_bond,
    const float* __restrict__ att_edge, const float* __restrict__ b_bond,
    unsigned short* __restrict__ WtA, unsigned short* __restrict__ WtB,
    float* __restrict__ u_edge, float* __restrict__ c_edge) {
    const int b = blockIdx.x;
    if (b < 512) {                      // WtA[n][k] = bf16(W_atom[k][n]), K=256
        int id = b * 256 + threadIdx.x;
        int n = id >> 8, k = id & 255;
        WtA[id] = f2bf(W_atom[(size_t)k * 512 + n]);
    } else if (b < 768) {               // WtB[n][k] = bf16(W_bond[k][n]), K=128
        int id = (b - 512) * 256 + threadIdx.x;
        int n = id >> 7, k = id & 127;
        WtB[id] = f2bf(W_bond[(size_t)k * 512 + n]);
    } else {                            // u_edge / c_edge
        int tid = (b - 768) * 256 + threadIdx.x;
        if (tid >= 1024) return;
        int h = tid >> 7, c = tid & 127;
        const float* wrow = W_bond + (size_t)c * 512 + h * 64;
        const float* ae = att_edge + h * 64;
        float s = 0.f;
        #pragma unroll 8
        for (int k = 0; k < 64; ++k) s += wrow[k] * ae[k];
        u_edge[h * 128 + c] = s;
        if (c == 0) {
            float cs = 0.f;
            const float* bb = b_bond + h * 64;
            for (int k = 0; k < 64; ++k) cs += bb[k] * ae[k];
            c_edge[h] = cs;
        }
    }
}

// ---------------------------------------------------------------------------
// STAGE1 (fused, r14 structure): blocks 0..2503 = atom GEMM (round-4 proven,
// XCD swizzle); blocks 2504..8753 = escore (32 bonds/block). The bf16 edgeB
// copy is emitted AT LOAD TIME from the staging registers (overlaps staging
// and the dot phase; no post-barrier LDS re-read). Union LDS (21152 B).
// ---------------------------------------------------------------------------
__global__ __launch_bounds__(256) void stage1_kernel(
    const float* __restrict__ x, const unsigned short* __restrict__ WtA,
    const float* __restrict__ b_atom, unsigned short* __restrict__ hA,
    const float* __restrict__ edge, const float* __restrict__ u_edge,
    const float* __restrict__ c_edge, float* __restrict__ score_edge,
    unsigned short* __restrict__ edgeB) {
    __shared__ __align__(16) unsigned char smem[21152];
    const int t = threadIdx.x;

    if (blockIdx.x < 2504) {
        // ================= ATOM GEMM path (M=20000, K=256, nbm=313) ========
        unsigned short* Als = (unsigned short*)smem;
        unsigned short* Bls = (unsigned short*)(smem + 8192);
        const int wgid = (blockIdx.x & 7) * 313 + (blockIdx.x >> 3);
        const int bn = wgid & 7;
        const int bm = wgid >> 3;
        const int w = t >> 6;
        const int l = t & 63;

        f32x4 acc[4] = {};

        for (int kk = 0; kk < 4; ++kk) {
            #pragma unroll
            for (int i = 0; i < 2; ++i) {
                int c = t + i * 256;
                int row = c >> 3;
                int k8 = (c & 7) << 3;
                int grow = (bm << 6) + row;
                float f[8];
                if (grow < N_ATOMS) {
                    const float* src = x + (size_t)grow * 256 + (kk << 6) + k8;
                    float4 v0 = *(const float4*)src;
                    float4 v1 = *(const float4*)(src + 4);
                    f[0] = v0.x; f[1] = v0.y; f[2] = v0.z; f[3] = v0.w;
                    f[4] = v1.x; f[5] = v1.y; f[6] = v1.z; f[7] = v1.w;
                } else {
                    #pragma unroll
                    for (int j = 0; j < 8; ++j) f[j] = 0.f;
                }
                union { unsigned short us[8]; uint4 v; } pk;
                #pragma unroll
                for (int j = 0; j < 8; ++j) pk.us[j] = f2bf(f[j]);
                int byte = ((row << 7) + (k8 << 1)) ^ ((row & 7) << 4);
                *(uint4*)((char*)Als + byte) = pk.v;
            }
            #pragma unroll
            for (int i = 0; i < 2; ++i) {
                int c = t + i * 256;
                int row = c >> 3;
                int k8 = (c & 7) << 3;
                int gn = (bn << 6) + row;
                uint4 v = *(const uint4*)(WtA + (size_t)gn * 256 + (kk << 6) + k8);
                int byte = ((row << 7) + (k8 << 1)) ^ ((row & 7) << 4);
                *(uint4*)((char*)Bls + byte) = v;
            }
            __syncthreads();

            const int m = l & 15;
            const int kg = (l >> 4) << 3;
            #pragma unroll
            for (int ks = 0; ks < 2; ++ks) {
                int kcol = (ks << 5) + kg;
                int arow = (w << 4) + m;
                short8v a = *(short8v*)((char*)Als +
                    (((arow << 7) + (kcol << 1)) ^ ((arow & 7) << 4)));
                #pragma unroll
                for (int nt = 0; nt < 4; ++nt) {
                    int nrow = (nt << 4) + m;
                    short8v bfr = *(short8v*)((char*)Bls +
                        (((nrow << 7) + (kcol << 1)) ^ ((nrow & 7) << 4)));
                    acc[nt] = __builtin_amdgcn_mfma_f32_16x16x32_bf16(a, bfr, acc[nt], 0, 0, 0);
                }
            }
            __syncthreads();
        }

        const int m = l & 15;
        const int rbase = (bm << 6) + (w << 4) + ((l >> 4) << 2);
        #pragma unroll
        for (int nt = 0; nt < 4; ++nt) {
            int col = (bn << 6) + (nt << 4) + m;
            float bv = b_atom[col];
            #pragma unroll
            for (int r = 0; r < 4; ++r) {
                int grow = rbase + r;
                if (grow < N_ATOMS) hA[(size_t)grow * 512 + col] = f2bf(acc[nt][r] + bv);
            }
        }
    } else {
        // ========== ESCORE + edgeB-at-load path: 32 bonds/block ============
        float* eL = (float*)smem;                 // 32*132 floats
        float* uL = (float*)(smem + 16896);       // 8*132 floats
        float* cL = (float*)(smem + 21120);       // 8 floats
        const size_t b0 = (size_t)(blockIdx.x - 2504) * 32;
        #pragma unroll
        for (int i = 0; i < 4; ++i) {
            int idx = i * 256 + t;                // f32x4 chunk 0..1023
            int row = idx >> 5, c4 = idx & 31;
            float4 v = *(const float4*)(edge + b0 * 128 + idx * 4);
            *(float4*)(eL + row * 132 + c4 * 4) = v;
            // bf16 edgeB straight from registers (overlaps staging + dot)
            uint2 pk;
            pk.x = (unsigned int)f2bf(v.x) | ((unsigned int)f2bf(v.y) << 16);
            pk.y = (unsigned int)f2bf(v.z) | ((unsigned int)f2bf(v.w) << 16);
            *(uint2*)(edgeB + (b0 + row) * 128 + c4 * 4) = pk;
        }
        {
            int h = t >> 5, c4 = t & 31;
            *(float4*)(uL + h * 132 + c4 * 4) = *(const float4*)(u_edge + h * 128 + c4 * 4);
        }
        if (t < 8) cL[t] = c_edge[t];
        __syncthreads();
        const int b2 = t >> 3, h = t & 7;
        float s = 0.f;
        #pragma unroll
        for (int c4 = 0; c4 < 32; ++c4) {
            float4 e = *(const float4*)(eL + b2 * 132 + c4 * 4);
            float4 u = *(const float4*)(uL + h * 132 + c4 * 4);
            s += e.x*u.x + e.y*u.y + e.z*u.z + e.w*u.w;
        }
        score_edge[(b0 + b2) * 8 + h] = s + cL[h];
    }
}

// ---------------------------------------------------------------------------
// Per-atom score tables from hA: s_src_all[n][h], s_dst_all[n][h].
// ---------------------------------------------------------------------------
__global__ __launch_bounds__(256) void sdots_kernel(
    const unsigned short* __restrict__ hA,
    const float* __restrict__ att_src, const float* __restrict__ att_dst,
    float* __restrict__ s_src_all, float* __restrict__ s_dst_all) {
    const int w = threadIdx.x >> 6, l = threadIdx.x & 63;
    const int n = blockIdx.x * 4 + w;
    if (n >= N_ATOMS) return;
    float4 s0 = *(const float4*)(att_src + l * 8);
    float4 s1 = *(const float4*)(att_src + l * 8 + 4);
    float4 d0 = *(const float4*)(att_dst + l * 8);
    float4 d1 = *(const float4*)(att_dst + l * 8 + 4);
    uint4 u = *(const uint4*)(hA + (size_t)n * 512 + l * 8);
    float fa[8];
    fa[0]=bf2f(u.x); fa[1]=bf2f(u.x>>16); fa[2]=bf2f(u.y); fa[3]=bf2f(u.y>>16);
    fa[4]=bf2f(u.z); fa[5]=bf2f(u.z>>16); fa[6]=bf2f(u.w); fa[7]=bf2f(u.w>>16);
    float ps = fa[0]*s0.x + fa[1]*s0.y + fa[2]*s0.z + fa[3]*s0.w
             + fa[4]*s1.x + fa[5]*s1.y + fa[6]*s1.z + fa[7]*s1.w;
    float pd = fa[0]*d0.x + fa[1]*d0.y + fa[2]*d0.z + fa[3]*d0.w
             + fa[4]*d1.x + fa[5]*d1.y + fa[6]*d1.z + fa[7]*d1.w;
    ps += __shfl_xor(ps, 1); ps += __shfl_xor(ps, 2); ps += __shfl_xor(ps, 4);
    pd += __shfl_xor(pd, 1); pd += __shfl_xor(pd, 2); pd += __shfl_xor(pd, 4);
    if ((l & 7) == 0) {
        s_src_all[n * 8 + (l >> 3)] = ps;
        s_dst_all[n * 8 + (l >> 3)] = pd;
    }
}

// ---------------------------------------------------------------------------
// Fused attention v7 (r14 proven): two-phase softmax, bf16 edge gather,
// bf16 hOut atom part. Lane l: head h=l>>3, channels l*8..+8, z (l&7)*16..+16.
// ---------------------------------------------------------------------------
__global__ __launch_bounds__(256) void attn_kernel(
    const unsigned short* __restrict__ hA,
    const unsigned short* __restrict__ edgeB,
    const float* __restrict__ s_src_all,
    const float* __restrict__ s_dst_all,
    const float* __restrict__ score_edge,
    const int* __restrict__ a2a,
    const int* __restrict__ a2b,
    unsigned short* __restrict__ hOut,
    unsigned short* __restrict__ Z) {
    const int w = threadIdx.x >> 6;
    const int l = threadIdx.x & 63;
    const int n = blockIdx.x * 4 + w;
    if (n >= N_ATOMS) return;
    const int h = l >> 3, sub = l & 7;

    const float ss = s_src_all[n * 8 + h];
    const int* pa = a2a + n * MAX_DEG;
    const int* pb = a2b + n * MAX_DEG;

    // ---- phase 1: all score gathers independent; exact softmax in regs ----
    float pw[12];
    #pragma unroll
    for (int d = 0; d < 12; ++d) {
        const int iad = pa[d];
        const int ibd = pb[d];
        float sd = s_dst_all[iad * 8 + h];
        float se = score_edge[ibd * 8 + h];
        float s = ss + sd + se;
        s = s > 0.f ? s : 0.2f * s;                 // leaky_relu(0.2)
        pw[d] = (iad != 0) ? s : -3e38f;            // sentinel for masked
    }
    float mx = fmaxf(
        fmaxf(fmaxf(fmaxf(pw[0], pw[1]), fmaxf(pw[2], pw[3])),
              fmaxf(fmaxf(pw[4], pw[5]), fmaxf(pw[6], pw[7]))),
        fmaxf(fmaxf(pw[8], pw[9]), fmaxf(pw[10], pw[11])));
    float lsum = 0.f;
    #pragma unroll
    for (int d = 0; d < 12; ++d) {
        pw[d] = __expf(pw[d] - mx);                 // masked: exp(-huge) = 0
        lsum += pw[d];
    }
    const float inv = lsum > 0.f ? 1.f / lsum : 0.f;

    // ---- phase 2: independent weighted accumulation (no chain) ----
    float acc[8], z[16];
    #pragma unroll
    for (int j = 0; j < 8; ++j) acc[j] = 0.f;
    #pragma unroll
    for (int j = 0; j < 16; ++j) z[j] = 0.f;

    #pragma unroll 2
    for (int d = 0; d < 12; ++d) {
        const int iad = pa[d];
        const int ibd = pb[d];
        const float p = pw[d];
        uint4 ua = *(const uint4*)(hA + (size_t)iad * 512 + l * 8);
        const unsigned short* ep = edgeB + (size_t)ibd * 128 + sub * 16;
        uint4 eb0 = *(const uint4*)(ep);
        uint4 eb1 = *(const uint4*)(ep + 8);

        float fa[8];
        fa[0]=bf2f(ua.x); fa[1]=bf2f(ua.x>>16); fa[2]=bf2f(ua.y); fa[3]=bf2f(ua.y>>16);
        fa[4]=bf2f(ua.z); fa[5]=bf2f(ua.z>>16); fa[6]=bf2f(ua.w); fa[7]=bf2f(ua.w>>16);

        #pragma unroll
        for (int j = 0; j < 8; ++j) acc[j] += p * fa[j];
        z[0]  += p * bf2f(eb0.x);       z[1]  += p * bf2f(eb0.x >> 16);
        z[2]  += p * bf2f(eb0.y);       z[3]  += p * bf2f(eb0.y >> 16);
        z[4]  += p * bf2f(eb0.z);       z[5]  += p * bf2f(eb0.z >> 16);
        z[6]  += p * bf2f(eb0.w);       z[7]  += p * bf2f(eb0.w >> 16);
        z[8]  += p * bf2f(eb1.x);       z[9]  += p * bf2f(eb1.x >> 16);
        z[10] += p * bf2f(eb1.y);       z[11] += p * bf2f(eb1.y >> 16);
        z[12] += p * bf2f(eb1.z);       z[13] += p * bf2f(eb1.z >> 16);
        z[14] += p * bf2f(eb1.w);       z[15] += p * bf2f(eb1.w >> 16);
    }

    // ---- atom part -> hOut (bf16) ----
    {
        union { unsigned int u[4]; uint4 v; } ap;
        #pragma unroll
        for (int i = 0; i < 4; ++i)
            ap.u[i] = (unsigned int)f2bf(acc[2*i] * inv)
                    | ((unsigned int)f2bf(acc[2*i+1] * inv) << 16);
        *(uint4*)(hOut + (size_t)n * 512 + l * 8) = ap.v;
    }

    // Z[n][h*128 + sub*16 .. +16] bf16: lane l -> 32B at l*32, coalesced
    union { unsigned int u[8]; uint4 v[2]; } zp;
    #pragma unroll
    for (int i = 0; i < 8; ++i)
        zp.u[i] = (unsigned int)f2bf(z[2*i] * inv)
                | ((unsigned int)f2bf(z[2*i+1] * inv) << 16);
    unsigned short* zdst = Z + (size_t)n * 1024 + l * 16;
    *(uint4*)zdst = zp.v[0];
    *(uint4*)(zdst + 8) = zp.v[1];
}

// ---------------------------------------------------------------------------
// Projection pass: out[n][h*64+j] = hOut + (Z[n][h] @ WtB_head) + b_bond.
// ---------------------------------------------------------------------------
__global__ __launch_bounds__(256, 4) void proj_kernel(
    const unsigned short* __restrict__ Z, const unsigned short* __restrict__ WtB,
    const float* __restrict__ b_bond, const unsigned short* __restrict__ hOut,
    float* __restrict__ out) {
    __shared__ unsigned short Bls[64 * 128];      // 16 KB
    const int t = threadIdx.x;
    const int w = t >> 6, l = t & 63;
    const int h = blockIdx.x & 7;                 // head
    const int mt = blockIdx.x >> 3;               // 0..312

    const int m16 = l & 15, g = l >> 4;
    const int arow = mt * 64 + (w << 4) + m16;

    const unsigned short* Zr = Z + (size_t)arow * 1024 + h * 128 + (g << 3);
    uint4 af[4];
    #pragma unroll
    for (int ks = 0; ks < 4; ++ks)
        af[ks] = *(const uint4*)(Zr + (ks << 5));

    {
        #pragma unroll
        for (int i = 0; i < 4; ++i) {
            int s = (w << 8) + (i << 6) + l;      // 0..1023
            int nrow = s >> 4;
            int kc = (s & 15) ^ (nrow & 7);
            const char* src = (const char*)WtB + (size_t)(h * 64 + nrow) * 256 + kc * 16;
            __builtin_amdgcn_global_load_lds(
                (const __attribute__((address_space(1))) void*)src,
                (__attribute__((address_space(3))) void*)((char*)Bls + (((w << 8) + (i << 6)) << 4)),
                16, 0, 0);
        }
    }
    __syncthreads();

    f32x4 acc[4] = {};
    #pragma unroll
    for (int ks = 0; ks < 4; ++ks) {
        short8v a = *(const short8v*)&af[ks];
        #pragma unroll
        for (int nt = 0; nt < 4; ++nt) {
            int nrow = (nt << 4) + m16;
            const short8v b = *(const short8v*)((const char*)Bls +
                ((nrow * 256 + (ks << 6) + (g << 4)) ^ ((nrow & 7) << 4)));
            acc[nt] = __builtin_amdgcn_mfma_f32_16x16x32_bf16(a, b, acc[nt], 0, 0, 0);
        }
    }

    const int rbase = mt * 64 + (w << 4) + (g << 2);
    #pragma unroll
    for (int nt = 0; nt < 4; ++nt) {
        int col = h * 64 + (nt << 4) + m16;
        float bv = b_bond[col];
        #pragma unroll
        for (int r = 0; r < 4; ++r) {
            int grow = rbase + r;
            if (grow < N_ATOMS) {
                float a0 = bf2f(hOut[(size_t)grow * 512 + col]);
                out[(size_t)grow * 512 + col] = a0 + acc[nt][r] + bv;
            }
        }
    }
}

// ---------------------------------------------------------------------------
extern "C" void kernel_launch(void* const* d_in, const int* in_sizes, int n_in,
                              void* d_out, int out_size, void* d_ws, size_t ws_size,
                              hipStream_t stream) {
    const float* x        = (const float*)d_in[0];
    const float* edge     = (const float*)d_in[1];
    const float* W_atom   = (const float*)d_in[2];
    const float* b_atom   = (const float*)d_in[3];
    const float* W_bond   = (const float*)d_in[4];
    const float* b_bond   = (const float*)d_in[5];
    const float* att_src  = (const float*)d_in[6];
    const float* att_dst  = (const float*)d_in[7];
    const float* att_edge = (const float*)d_in[8];
    const int*   a2a      = (const int*)d_in[9];
    const int*   a2b      = (const int*)d_in[10];
    float* out = (float*)d_out;

    char* ws = (char*)d_ws;
    unsigned short* hA    = (unsigned short*)ws;                    // 20,480,000
    unsigned short* Zb    = (unsigned short*)(ws + 20480000);       // 40,960,000
    unsigned short* WtA   = (unsigned short*)(ws + 61440000);       // 262,144
    unsigned short* WtB   = (unsigned short*)(ws + 61702144);       // 131,072
    float* s_src_all      = (float*)(ws + 61833216);                // 640,000
    float* s_dst_all      = (float*)(ws + 62473216);                // 640,000
    float* score_edge     = (float*)(ws + 63113216);                // 6,400,000
    float* u_edge         = (float*)(ws + 69513216);                // 4,096
    float* c_edge         = (float*)(ws + 69517312);                // 64 (pad)
    unsigned short* hOut  = (unsigned short*)(ws + 69517376);       // 20,480,000
    unsigned short* edgeB = (unsigned short*)(ws + 89997376);       // 51,200,000

    prep_kernel<<<772, 256, 0, stream>>>(W_atom, W_bond, att_edge, b_bond,
                                         WtA, WtB, u_edge, c_edge);

    // fused: atom GEMM (2504 blocks) + escore/edgeB-at-load (6250 blocks)
    stage1_kernel<<<8754, 256, 0, stream>>>(x, WtA, b_atom, hA,
                                            edge, u_edge, c_edge, score_edge, edgeB);

    sdots_kernel<<<5000, 256, 0, stream>>>(hA, att_src, att_dst, s_src_all, s_dst_all);

    attn_kernel<<<5000, 256, 0, stream>>>(
        hA, edgeB, s_src_all, s_dst_all, score_edge, a2a, a2b, hOut, Zb);

    proj_kernel<<<313 * 8, 256, 0, stream>>>(Zb, WtB, b_bond, hOut, out);
}